// Round 7
// baseline (267.845 us; speedup 1.0000x reference)
//
#include <hip/hip_runtime.h>
#include <math.h>

// Magnus-0 midpoint propagation of a damped oscillator.
//   out[0] = x0;  out[i+1] = E_i @ out[i],  E_i = expm(dt_i * A(t_mid_i)) (2x2)
// Structure (2 kernels):
//   KA chunk_E: one 64-thread block per 64 steps. Computes E_j (fp64 math,
//      fp32 store) AND TWO 32-step fp64 products via a 5-level shfl_xor
//      butterfly (offsets <32 stay within each 32-lane half).
//   KB propagate: per (32-step chunk, column-quad-group) block.
//      CS=32 x CPT=4 x TPB=256 -> 1024 blocks / 16 waves per CU (the measured
//      optimum: 512 blk=304.6us[NT], 1024=274.5[NT]/266.8[WB], 2048=279.1[NT])
//      with 16 B/lane dwordx4 REGULAR stores (R6: write-back beats NT by 8us).
//      Prefix Q_c via fp64 Kogge-Stone scan in LDS (measured neutral).
// HBM-write-bound: 256 MiB output -> ~42 us floor at ~6.5 TB/s. Most of the
// measured dur is harness re-poison fill (~205 us of fillBuffer dispatches
// at ~6.5 TB/s in rocprof), which we cannot touch.

#define CS    32     // time steps per chunk (KB granularity)
#define TPB   256
#define CPT   4      // columns per thread (float4 stores)
#define MAXCH 256    // max 32-step chunks supported (T <= 8193 here)

// ---------------- KA: per-step propagators + two 32-step products ----------------
__global__ __launch_bounds__(64) void chunk_E(
        const float* __restrict__ t,
        const float* __restrict__ p_w2,
        const float* __restrict__ p_g0,
        const float* __restrict__ p_gamp,
        const float* __restrict__ p_od,
        float4* __restrict__ E,
        double* __restrict__ M,     // [2*gridDim][4] fp64 32-step products
        int nsteps) {
    const int c = blockIdx.x;                 // 64-step super-chunk
    const int j = c * 64 + threadIdx.x;
    // Identity for lanes past the end (last partial chunk).
    double e00 = 1.0, e01 = 0.0, e10 = 0.0, e11 = 1.0;
    if (j < nsteps) {
        double w2 = (double)p_w2[0], g0 = (double)p_g0[0];
        double gamp = (double)p_gamp[0], od = (double)p_od[0];
        double t0 = (double)t[j], t1 = (double)t[j + 1];
        double dt = t1 - t0;
        double tm = t0 + 0.5 * dt;
        double gamma = g0 * (1.0 + gamp * sin(od * tm));
        // M = [[0, dt], [-w2*dt, -gamma*dt]]
        double m = -0.5 * gamma * dt;            // tr(M)/2
        double delta = m * m - w2 * dt * dt;     // m^2 - det(M)
        double s = sqrt(fabs(delta));
        double ss = fmax(s, 1e-12);
        double f, g;
        if (delta >= 0.0) {
            f = cosh(s); g = sinh(ss) / ss;      // not taken for this regime
        } else {
            double sn, cz;
            sincos(ss, &sn, &cz);                // one transcendental call
            f = cz; g = sn / ss;
        }
        double em = exp(m);
        // N = M - m*I = [[-m, dt], [-w2*dt, m]]
        e00 = em * (f - g * m);
        e01 = em * (g * dt);
        e10 = em * (-g * w2 * dt);
        e11 = em * (f + g * m);
        E[j] = make_float4((float)e00, (float)e01, (float)e10, (float)e11);
    }
    // 5-level butterfly: product of each 32-lane half (later steps on the left).
    #pragma unroll
    for (int k = 0; k < 5; ++k) {
        const int hi = (threadIdx.x >> k) & 1;
        double p00 = __shfl_xor(e00, 1 << k, 64);
        double p01 = __shfl_xor(e01, 1 << k, 64);
        double p10 = __shfl_xor(e10, 1 << k, 64);
        double p11 = __shfl_xor(e11, 1 << k, 64);
        // A = upper-half product, B = lower-half product; new = A*B.
        double a00 = hi ? e00 : p00, a01 = hi ? e01 : p01;
        double a10 = hi ? e10 : p10, a11 = hi ? e11 : p11;
        double b00 = hi ? p00 : e00, b01 = hi ? p01 : e01;
        double b10 = hi ? p10 : e10, b11 = hi ? p11 : e11;
        e00 = a00 * b00 + a01 * b10;
        e01 = a00 * b01 + a01 * b11;
        e10 = a10 * b00 + a11 * b10;
        e11 = a10 * b01 + a11 * b11;
    }
    if ((threadIdx.x & 31) == 0) {
        const int idx = 2 * c + (threadIdx.x >> 5);   // 32-step chunk index
        M[4 * idx + 0] = e00; M[4 * idx + 1] = e01;
        M[4 * idx + 2] = e10; M[4 * idx + 3] = e11;
    }
}

// ---------------- KB: parallel prefix + propagate + write rows ----------------
__global__ __launch_bounds__(TPB) void propagate(
        const float4* __restrict__ E,
        const double* __restrict__ M,
        const float* __restrict__ x0,
        float* __restrict__ out,
        int nsteps, int B, int bgroups, int nch) {
    __shared__ float4 Es[CS];                // 512 B
    __shared__ double Pl[MAXCH][5];          // scan buffer, padded stride (10 KB)
    const int c   = blockIdx.x / bgroups;
    const int bg  = blockIdx.x % bgroups;
    const int tid = threadIdx.x;
    const int j0  = c * CS;
    const int n   = min(CS, nsteps - j0);

    if (tid < n) Es[tid] = E[j0 + tid];
    for (int i = tid; i < 4 * nch; i += TPB)   // stage M_0..M_{nch-1}
        Pl[i >> 2][i & 3] = M[i];
    __syncthreads();

    // Kogge-Stone inclusive scan: Pl[i] <- M_i * M_{i-1} * ... * M_0 (fp64).
    // All threads reach every barrier (guards only on the LDS work).
    double p00 = 0, p01 = 0, p10 = 0, p11 = 0;
    if (tid < nch) {
        p00 = Pl[tid][0]; p01 = Pl[tid][1]; p10 = Pl[tid][2]; p11 = Pl[tid][3];
    }
    for (int d = 1; d < nch; d <<= 1) {
        double b00 = 0, b01 = 0, b10 = 0, b11 = 0;
        const bool act = (tid >= d) && (tid < nch);
        if (act) {
            b00 = Pl[tid - d][0]; b01 = Pl[tid - d][1];
            b10 = Pl[tid - d][2]; b11 = Pl[tid - d][3];
        }
        __syncthreads();                      // all reads of step-k values done
        if (act) {
            double n00 = p00 * b00 + p01 * b10;   // seg[i] <- seg[i] * seg[i-d]
            double n01 = p00 * b01 + p01 * b11;
            double n10 = p10 * b00 + p11 * b10;
            double n11 = p10 * b01 + p11 * b11;
            p00 = n00; p01 = n01; p10 = n10; p11 = n11;
            Pl[tid][0] = p00; Pl[tid][1] = p01; Pl[tid][2] = p10; Pl[tid][3] = p11;
        }
        __syncthreads();                      // step-(k+1) values visible
    }
    // Q_c = exclusive prefix = Pl[c-1] (identity for c == 0).
    float q00, q01, q10, q11;
    if (c == 0) { q00 = 1.f; q01 = 0.f; q10 = 0.f; q11 = 1.f; }
    else {
        q00 = (float)Pl[c - 1][0]; q01 = (float)Pl[c - 1][1];
        q10 = (float)Pl[c - 1][2]; q11 = (float)Pl[c - 1][3];
    }

    const int b = CPT * (bg * TPB + tid);    // four consecutive columns
    if (b >= B) return;                      // no barriers past this point

    const float4 xr0 = *(const float4*)(x0 + b);       // row 0, cols b..b+3
    const float4 xr1 = *(const float4*)(x0 + B + b);   // row 1, cols b..b+3
    float a0 = q00 * xr0.x + q01 * xr1.x, c0 = q10 * xr0.x + q11 * xr1.x;
    float a1 = q00 * xr0.y + q01 * xr1.y, c1 = q10 * xr0.y + q11 * xr1.y;
    float a2 = q00 * xr0.z + q01 * xr1.z, c2 = q10 * xr0.z + q11 * xr1.z;
    float a3 = q00 * xr0.w + q01 * xr1.w, c3 = q10 * xr0.w + q11 * xr1.w;

    if (c == 0) {                            // row 0 = x0 verbatim
        *(float4*)(out + b) = xr0;
        *(float4*)(out + B + b) = xr1;
    }

    float* o = out + (size_t)(j0 + 1) * 2 * (size_t)B + b;
    #pragma unroll 4
    for (int jj = 0; jj < n; ++jj) {
        float4 e = Es[jj];
        float na0 = e.x * a0 + e.y * c0, nc0 = e.z * a0 + e.w * c0;
        float na1 = e.x * a1 + e.y * c1, nc1 = e.z * a1 + e.w * c1;
        float na2 = e.x * a2 + e.y * c2, nc2 = e.z * a2 + e.w * c2;
        float na3 = e.x * a3 + e.y * c3, nc3 = e.z * a3 + e.w * c3;
        a0 = na0; c0 = nc0; a1 = na1; c1 = nc1;
        a2 = na2; c2 = nc2; a3 = na3; c3 = nc3;
        *(float4*)o       = make_float4(a0, a1, a2, a3);   // regular stores
        *(float4*)(o + B) = make_float4(c0, c1, c2, c3);
        o += 2 * B;
    }
}

extern "C" void kernel_launch(void* const* d_in, const int* in_sizes, int n_in,
                              void* d_out, int out_size, void* d_ws, size_t ws_size,
                              hipStream_t stream) {
    const float* t    = (const float*)d_in[0];
    const float* x0   = (const float*)d_in[1];
    const float* w2   = (const float*)d_in[2];
    const float* g0   = (const float*)d_in[3];
    const float* gamp = (const float*)d_in[4];
    const float* od   = (const float*)d_in[5];
    float* out = (float*)d_out;

    const int T = in_sizes[0];
    const int B = in_sizes[1] / 2;
    const int nsteps = T - 1;
    const int nch64 = (nsteps + 63) / 64;                    // chunk_E blocks
    const int nch   = (nsteps + CS - 1) / CS;                // 32-step chunks (256)
    const int bgroups = (B + CPT * TPB - 1) / (CPT * TPB);   // 4 for B=4096

    // Workspace layout: E (nsteps float4) | M (2*nch64 double4)
    float4* E = (float4*)d_ws;
    double* M = (double*)((char*)d_ws + (((size_t)nsteps * 16 + 255) & ~(size_t)255));

    chunk_E<<<nch64, 64, 0, stream>>>(t, w2, g0, gamp, od, E, M, nsteps);
    propagate<<<nch * bgroups, TPB, 0, stream>>>(E, M, x0, out, nsteps, B, bgroups, nch);
}